// Round 6
// baseline (862.781 us; speedup 1.0000x reference)
//
#include <hip/hip_runtime.h>
#include <hip/hip_bf16.h>

typedef __attribute__((ext_vector_type(8))) short short8;
typedef __attribute__((ext_vector_type(4))) float f32x4;
typedef __attribute__((ext_vector_type(16))) float f32x16;
typedef unsigned short u16;
typedef unsigned int u32;

#define NTOK   8192
#define DMODEL 1024
#define DFF    4096
#define NEXP   8
#define NPAIR  (NTOK * 2)
#define PADM   256            // per-expert padding
#define MT1    72             // ceil((16384 + 8*255)/256)
#define PPAD   (MT1 * PADM)   // 18432

// ---- workspace layout (bytes) ----
#define OFF_XB   0ull
#define OFF_W1T  (OFF_XB  + (size_t)NTOK * DMODEL * 2)
#define OFF_W2T  (OFF_W1T + (size_t)NEXP * DFF * DMODEL * 2)
#define OFF_W3T  (OFF_W2T + (size_t)NEXP * DFF * DMODEL * 2)
#define OFF_H    (OFF_W3T + (size_t)NEXP * DMODEL * DFF * 2)
#define OFF_TOK  (OFF_H   + (size_t)PPAD * DFF * 2)
#define OFF_WGT  (OFF_TOK + (size_t)PPAD * 4)
#define OFF_CNT  (OFF_WGT + (size_t)PPAD * 4)
#define OFF_CUR  (OFF_CNT + 64)
#define OFF_OFFP (OFF_CUR + 64)
#define WS_END   (OFF_OFFP + 64)

#define GLOAD16(gp, lp)                                                        \
  __builtin_amdgcn_global_load_lds(                                            \
      (const __attribute__((address_space(1))) u32*)(gp),                      \
      (__attribute__((address_space(3))) u32*)(lp), 16, 0, 0)

__device__ __forceinline__ u16 f2bu(float f) {
  __hip_bfloat16 b = __float2bfloat16(f);
  return __builtin_bit_cast(u16, b);
}

// ---------------- conversion kernels ----------------

__global__ __launch_bounds__(256) void cvt_x_k(const float* __restrict__ x,
                                               u16* __restrict__ xb) {
  int i = blockIdx.x * 256 + threadIdx.x;
  float4 v = ((const float4*)x)[i];
  unsigned long long pk = (unsigned long long)f2bu(v.x) |
                          ((unsigned long long)f2bu(v.y) << 16) |
                          ((unsigned long long)f2bu(v.z) << 32) |
                          ((unsigned long long)f2bu(v.w) << 48);
  ((unsigned long long*)xb)[i] = pk;
}

// transpose [R][C] fp32 -> [C][R] bf16, batched over blockIdx.z
__global__ __launch_bounds__(256) void tr_cvt_k(const float* __restrict__ src,
                                                u16* __restrict__ dst, int R, int C) {
  src += (size_t)blockIdx.z * R * C;
  dst += (size_t)blockIdx.z * R * C;
  int c0 = blockIdx.x * 64, r0 = blockIdx.y * 64;
  __shared__ float tile[64][65];
  int tid = threadIdx.x;
  int f4 = tid & 15, rr = tid >> 4;
#pragma unroll
  for (int p = 0; p < 4; ++p) {
    int r = rr + p * 16;
    float4 v = *(const float4*)(src + (size_t)(r0 + r) * C + c0 + f4 * 4);
    tile[r][f4 * 4 + 0] = v.x; tile[r][f4 * 4 + 1] = v.y;
    tile[r][f4 * 4 + 2] = v.z; tile[r][f4 * 4 + 3] = v.w;
  }
  __syncthreads();
  int ch = tid & 7, cc = tid >> 3;
#pragma unroll
  for (int p = 0; p < 2; ++p) {
    int c = cc + p * 32;
    short8 s;
#pragma unroll
    for (int j = 0; j < 8; ++j) s[j] = (short)f2bu(tile[ch * 8 + j][c]);
    *(short8*)(dst + (size_t)(c0 + c) * R + r0 + ch * 8) = s;
  }
}

// ---------------- routing kernels ----------------

__global__ __launch_bounds__(256) void count_k(const int* __restrict__ ei,
                                               int* __restrict__ cnt) {
  int i = blockIdx.x * 256 + threadIdx.x;
  atomicAdd(&cnt[ei[i]], 1);
}

__global__ void scan_k(const int* __restrict__ cnt, int* __restrict__ offp) {
  if (threadIdx.x == 0) {
    int a = 0;
#pragma unroll
    for (int e = 0; e < NEXP; ++e) { offp[e] = a; a += (cnt[e] + PADM - 1) & ~(PADM - 1); }
    offp[NEXP] = a;
  }
}

__global__ __launch_bounds__(256) void scatter_k(const int* __restrict__ ei,
                                                 const float* __restrict__ ew,
                                                 const int* __restrict__ offp,
                                                 int* __restrict__ cur,
                                                 int* __restrict__ tok,
                                                 float* __restrict__ wg) {
  int i = blockIdx.x * 256 + threadIdx.x;
  int e = ei[i];
  int p = offp[e] + atomicAdd(&cur[e], 1);
  tok[p] = i >> 1;
  wg[p] = ew[i];
}

// ---------------- stage 1: h = silu(x@W1) * (x@W2), grouped ----------------
// r5 skeleton (3-buffer, BK=32, counted vmcnt(4), 1 barrier/step) with MFMA
// switched to 32x32x16 (2495 TF ubench vs 2075 for 16x16x32; half the issue
// slots). Wave tile 128M x 32N per B-matrix; 16 MFMA/wave/step.
// A/B frag: row(col)=lane&31, k = kk*16 + (lane>>5)*8 + j.
// C/D: col=lane&31, row=(reg&3)+8*(reg>>2)+4*(lane>>5)   [m74/m101-verified]

#define S1_BUF 16384   // u16 per buffer: A 8192 | B1 4096 | B2 4096
#define S1_NK  32      // 1024 / 32

__global__ __launch_bounds__(512, 2) void stage1_k(const u16* __restrict__ xb,
                                                   const u16* __restrict__ w1t,
                                                   const u16* __restrict__ w2t,
                                                   u16* __restrict__ h,
                                                   const int* __restrict__ tok,
                                                   const int* __restrict__ offp) {
  extern __shared__ __align__(16) u16 lds[];   // 3 * 32 KB = 98304 B
  const int r0 = blockIdx.y * PADM;
  if (r0 >= offp[NEXP]) return;
  int e = 0;
#pragma unroll
  for (int q = 0; q < 7; ++q) e += (offp[e + 1] <= r0) ? 1 : 0;
  const int n0 = blockIdx.x * 128;
  const int tid = threadIdx.x;
  const int lane = tid & 63, w = tid >> 6;
  const int wm = w >> 2, wn = w & 3;

  // ---- staging source pointers (per-lane; source-side slot swizzle) ----
  const int sl = lane & 3, rl = lane >> 2;
  const u16* aga[2];
  int adb[2];
#pragma unroll
  for (int j = 0; j < 2; ++j) {
    int row = w * 32 + j * 16 + rl;
    int t = tok[r0 + row];
    aga[j] = xb + (size_t)t * DMODEL + ((sl ^ ((row >> 1) & 3)) << 3);
    adb[j] = (w * 32 + j * 16) * 32;
  }
  const u16* w1e = w1t + (size_t)e * DFF * DMODEL;
  const u16* w2e = w2t + (size_t)e * DFF * DMODEL;
  const u16* bg1; const u16* bg2;
  int bdb;
  {
    int row = w * 16 + rl;
    size_t ro = (size_t)(n0 + row) * DMODEL + ((sl ^ ((row >> 1) & 3)) << 3);
    bg1 = w1e + ro; bg2 = w2e + ro;
    bdb = (w * 16) * 32;
  }

  // ---- fragment read offsets (u16 idx); kk toggles slot bit1 -> ^16 ----
  int aoff[4], boff;
  {
    int kg0 = lane >> 5;
#pragma unroll
    for (int mb = 0; mb < 4; ++mb) {
      int row = wm * 128 + mb * 32 + (lane & 31);
      aoff[mb] = row * 32 + ((kg0 ^ ((row >> 1) & 3)) << 3);
    }
    int col = wn * 32 + (lane & 31);
    boff = col * 32 + ((kg0 ^ ((col >> 1) & 3)) << 3);
  }

  f32x16 accg[4], accv[4];
#pragma unroll
  for (int mb = 0; mb < 4; ++mb) {
#pragma unroll
    for (int r = 0; r < 16; ++r) { accg[mb][r] = 0.f; accv[mb][r] = 0.f; }
  }

#define S1_ISSUE(Q, KO)                                                        \
  do {                                                                         \
    GLOAD16(aga[0] + (KO), (Q) + adb[0]);                                      \
    GLOAD16(aga[1] + (KO), (Q) + adb[1]);                                      \
    GLOAD16(bg1 + (KO), (Q) + 8192 + bdb);                                     \
    GLOAD16(bg2 + (KO), (Q) + 12288 + bdb);                                    \
  } while (0)

  // ---- prologue: issue K-step 0 (buf0) and 1 (buf1); wait step 0 only ----
  S1_ISSUE(lds, 0);
  S1_ISSUE(lds + S1_BUF, 32);
  asm volatile("s_waitcnt vmcnt(4)" ::: "memory");
  __builtin_amdgcn_s_barrier();
  __builtin_amdgcn_sched_barrier(0);

#define S1_STEP(P, KC, ISSUE)                                                  \
  {                                                                            \
    const u16* Ab  = lds + (P) * S1_BUF;                                       \
    const u16* B1b = Ab + 8192;                                                \
    const u16* B2b = Ab + 12288;                                               \
    short8 af[4][2], b1f[2], b2f[2];                                           \
    _Pragma("unroll") for (int mb = 0; mb < 4; ++mb)                           \
      _Pragma("unroll") for (int kk = 0; kk < 2; ++kk)                         \
        af[mb][kk] = *(const short8*)(Ab + (aoff[mb] ^ (kk << 4)));            \
    _Pragma("unroll") for (int kk = 0; kk < 2; ++kk) {                         \
      b1f[kk] = *(const short8*)(B1b + (boff ^ (kk << 4)));                    \
      b2f[kk] = *(const short8*)(B2b + (boff ^ (kk << 4)));                    \
    }                                                                          \
    if (ISSUE) S1_ISSUE(lds + (((P) + 2) % 3) * S1_BUF, ((KC) + 2) * 32);      \
    __builtin_amdgcn_s_setprio(1);                                             \
    _Pragma("unroll") for (int kk = 0; kk < 2; ++kk)                           \
      _Pragma("unroll") for (int mb = 0; mb < 4; ++mb) {                       \
        accg[mb] = __builtin_amdgcn_mfma_f32_32x32x16_bf16(                    \
            af[mb][kk], b1f[kk], accg[mb], 0, 0, 0);                           \
        accv[mb] = __builtin_amdgcn_mfma_f32_32x32x16_bf16(                    \
            af[mb][kk], b2f[kk], accv[mb], 0, 0, 0);                           \
      }                                                                        \
    __builtin_amdgcn_s_setprio(0);                                             \
    if (ISSUE) asm volatile("s_waitcnt vmcnt(4)" ::: "memory");                \
    else       asm volatile("s_waitcnt vmcnt(0)" ::: "memory");                \
    __builtin_amdgcn_s_barrier();                                              \
    __builtin_amdgcn_sched_barrier(0);                                         \
  }

  for (int kc = 0; kc < S1_NK - 2; kc += 3) {
    S1_STEP(0, kc, 1)
    S1_STEP(1, kc + 1, 1)
    S1_STEP(2, kc + 2, 1)
  }
  S1_STEP(0, S1_NK - 2, 0)
  S1_STEP(1, S1_NK - 1, 0)
#undef S1_STEP
#undef S1_ISSUE

  // ---- epilogue: silu(gate) * val -> h (32x32 C/D mapping) ----
  const int ecol = n0 + wn * 32 + (lane & 31);
  const int erow0 = r0 + wm * 128 + 4 * (lane >> 5);
#pragma unroll
  for (int mb = 0; mb < 4; ++mb)
#pragma unroll
    for (int r = 0; r < 16; ++r) {
      int erow = erow0 + mb * 32 + (r & 3) + 8 * (r >> 2);
      float g = accg[mb][r];
      float v = accv[mb][r];
      float s = g / (1.f + __expf(-g));
      h[(size_t)erow * DFF + ecol] = f2bu(s * v);
    }
}

// ---------------- stage 2: out += p * (h @ W3), grouped ----------------
// r5-style 3-buffer BK=32 counted-vmcnt pipeline. Tile 256x128, 512 thr,
// 8 waves as 4M x 2N (wave tile 64x64) to keep VGPR <= 128 so the 72 KB
// LDS allows 2 blocks/CU (cross-block overlap).

#define S2_BUF 12288   // u16 per buffer: A 8192 (256x32) | B 4096 (128x32)
#define S2_NK  128     // 4096 / 32

__global__ __launch_bounds__(512, 4) void stage2_k(const u16* __restrict__ h,
                                                   const u16* __restrict__ w3t,
                                                   float* __restrict__ out,
                                                   const int* __restrict__ tok,
                                                   const float* __restrict__ wg,
                                                   const int* __restrict__ offp) {
  extern __shared__ __align__(16) u16 lds[];   // 3 * 24 KB = 73728 B
  const int r0 = blockIdx.y * 256;
  if (r0 >= offp[NEXP]) return;
  int e = 0;
#pragma unroll
  for (int q = 0; q < 7; ++q) e += (offp[e + 1] <= r0) ? 1 : 0;
  const int n0 = blockIdx.x * 128;
  const int tid = threadIdx.x;
  const int lane = tid & 63, w = tid >> 6;
  const int wm = w >> 1, wn = w & 1;

  const int sl = lane & 3, rl = lane >> 2;
  const u16* aga[2];
  int adb[2];
#pragma unroll
  for (int j = 0; j < 2; ++j) {
    int row = w * 32 + j * 16 + rl;
    aga[j] = h + (size_t)(r0 + row) * DFF + ((sl ^ ((row >> 1) & 3)) << 3);
    adb[j] = (w * 32 + j * 16) * 32;
  }
  const u16* w3e = w3t + (size_t)e * DMODEL * DFF;
  const u16* bga;
  int bdb;
  {
    int row = w * 16 + rl;
    bga = w3e + (size_t)(n0 + row) * DFF + ((sl ^ ((row >> 1) & 3)) << 3);
    bdb = (w * 16) * 32;
  }

  int aoff[4], boff[4];
  {
    int ks = lane >> 4;
#pragma unroll
    for (int mi = 0; mi < 4; ++mi) {
      int row = wm * 64 + mi * 16 + (lane & 15);
      aoff[mi] = row * 32 + ((ks ^ ((row >> 1) & 3)) << 3);
    }
#pragma unroll
    for (int ni = 0; ni < 4; ++ni) {
      int col = wn * 64 + ni * 16 + (lane & 15);
      boff[ni] = col * 32 + ((ks ^ ((col >> 1) & 3)) << 3);
    }
  }

  f32x4 acc[4][4];
  const f32x4 zero = {0.f, 0.f, 0.f, 0.f};
#pragma unroll
  for (int mi = 0; mi < 4; ++mi)
#pragma unroll
    for (int ni = 0; ni < 4; ++ni) acc[mi][ni] = zero;

#define S2_ISSUE(Q, KO)                                                        \
  do {                                                                         \
    GLOAD16(aga[0] + (KO), (Q) + adb[0]);                                      \
    GLOAD16(aga[1] + (KO), (Q) + adb[1]);                                      \
    GLOAD16(bga + (KO), (Q) + 8192 + bdb);                                     \
  } while (0)

  S2_ISSUE(lds, 0);
  S2_ISSUE(lds + S2_BUF, 32);
  asm volatile("s_waitcnt vmcnt(3)" ::: "memory");
  __builtin_amdgcn_s_barrier();
  __builtin_amdgcn_sched_barrier(0);

#define S2_STEP(P, KC, ISSUE)                                                  \
  {                                                                            \
    const u16* Ab = lds + (P) * S2_BUF;                                        \
    const u16* Bb = Ab + 8192;                                                 \
    short8 bf[4], af0, af1;                                                    \
    _Pragma("unroll") for (int ni = 0; ni < 4; ++ni)                           \
      bf[ni] = *(const short8*)(Bb + boff[ni]);                                \
    af0 = *(const short8*)(Ab + aoff[0]);                                      \
    af1 = *(const short8*)(Ab + aoff[1]);                                      \
    if (ISSUE) S2_ISSUE(lds + (((P) + 2) % 3) * S2_BUF, ((KC) + 2) * 32);      \
    __builtin_amdgcn_s_setprio(1);                                             \
    _Pragma("unroll") for (int ni = 0; ni < 4; ++ni) {                         \
      acc[0][ni] = __builtin_amdgcn_mfma_f32_16x16x32_bf16(                    \
          af0, bf[ni], acc[0][ni], 0, 0, 0);                                   \
      acc[1][ni] = __builtin_amdgcn_mfma_f32_16x16x32_bf16(                    \
          af1, bf[ni], acc[1][ni], 0, 0, 0);                                   \
    }                                                                          \
    __builtin_amdgcn_s_setprio(0);                                             \
    af0 = *(const short8*)(Ab + aoff[2]);                                      \
    af1 = *(const short8*)(Ab + aoff[3]);                                      \
    __builtin_amdgcn_s_setprio(1);                                             \
    _Pragma("unroll") for (int ni = 0; ni < 4; ++ni) {                         \
      acc[2][ni] = __builtin_amdgcn_mfma_f32_16x16x32_bf16(                    \
          af0, bf[ni], acc[2][ni], 0, 0, 0);                                   \
      acc[3][ni] = __builtin_amdgcn_mfma_f32_16x16x32_bf16(                    \
          af1, bf[ni], acc[3][ni], 0, 0, 0);                                   \
    }                                                                          \
    __builtin_amdgcn_s_setprio(0);                                             \
    if (ISSUE) asm volatile("s_waitcnt vmcnt(3)" ::: "memory");                \
    else       asm volatile("s_waitcnt vmcnt(0)" ::: "memory");                \
    __builtin_amdgcn_s_barrier();                                              \
    __builtin_amdgcn_sched_barrier(0);                                         \
  }

  for (int kc = 0; kc < S2_NK - 2; kc += 3) {
    S2_STEP(0, kc, 1)
    S2_STEP(1, kc + 1, 1)
    S2_STEP(2, kc + 2, 1)
  }
  S2_STEP(0, S2_NK - 2, 0)
  S2_STEP(1, S2_NK - 1, 0)
#undef S2_STEP
#undef S2_ISSUE

  const int prow = r0 + wm * 64 + ((lane >> 4) << 2);
  const int pcolb = n0 + wn * 64 + (lane & 15);
#pragma unroll
  for (int mi = 0; mi < 4; ++mi)
#pragma unroll
    for (int j = 0; j < 4; ++j) {
      int pos = prow + mi * 16 + j;
      float p = wg[pos];
      if (p != 0.f) {
        int t = tok[pos];
#pragma unroll
        for (int ni = 0; ni < 4; ++ni)
          atomicAdd(&out[(size_t)t * DMODEL + pcolb + ni * 16], p * acc[mi][ni][j]);
      }
    }
}

// ---------------- launch ----------------

extern "C" void kernel_launch(void* const* d_in, const int* in_sizes, int n_in,
                              void* d_out, int out_size, void* d_ws, size_t ws_size,
                              hipStream_t stream) {
  (void)in_sizes; (void)n_in;
  const float* x  = (const float*)d_in[0];
  const int*   ei = (const int*)d_in[1];
  const float* ew = (const float*)d_in[2];
  const float* w1 = (const float*)d_in[3];
  const float* w2 = (const float*)d_in[4];
  const float* w3 = (const float*)d_in[5];
  float* out = (float*)d_out;
  char* ws = (char*)d_ws;

  hipMemsetAsync(out, 0, (size_t)out_size * sizeof(float), stream);
  if (ws_size < WS_END) return;   // ws too small: leave zeros (diagnosable absmax)

  u16* xb   = (u16*)(ws + OFF_XB);
  u16* w1t  = (u16*)(ws + OFF_W1T);
  u16* w2t  = (u16*)(ws + OFF_W2T);
  u16* w3t  = (u16*)(ws + OFF_W3T);
  u16* hb   = (u16*)(ws + OFF_H);
  int* tok  = (int*)(ws + OFF_TOK);
  float* wg = (float*)(ws + OFF_WGT);
  int* cnt  = (int*)(ws + OFF_CNT);
  int* cur  = (int*)(ws + OFF_CUR);
  int* offp = (int*)(ws + OFF_OFFP);

  hipMemsetAsync(ws + OFF_TOK, 0, (size_t)(WS_END - OFF_TOK), stream);

  hipFuncSetAttribute(reinterpret_cast<const void*>(stage1_k),
                      hipFuncAttributeMaxDynamicSharedMemorySize, 98304);
  hipFuncSetAttribute(reinterpret_cast<const void*>(stage2_k),
                      hipFuncAttributeMaxDynamicSharedMemorySize, 73728);

  cvt_x_k<<<dim3(NTOK * DMODEL / 4 / 256), 256, 0, stream>>>(x, xb);
  tr_cvt_k<<<dim3(DFF / 64, DMODEL / 64, NEXP), 256, 0, stream>>>(w1, w1t, DMODEL, DFF);
  tr_cvt_k<<<dim3(DFF / 64, DMODEL / 64, NEXP), 256, 0, stream>>>(w2, w2t, DMODEL, DFF);
  tr_cvt_k<<<dim3(DMODEL / 64, DFF / 64, NEXP), 256, 0, stream>>>(w3, w3t, DFF, DMODEL);
  count_k<<<dim3(NPAIR / 256), 256, 0, stream>>>(ei, cnt);
  scan_k<<<1, 64, 0, stream>>>(cnt, offp);
  scatter_k<<<dim3(NPAIR / 256), 256, 0, stream>>>(ei, ew, offp, cur, tok, wg);
  stage1_k<<<dim3(DFF / 128, MT1), 512, 98304, stream>>>(xb, w1t, w2t, hb, tok, offp);
  stage2_k<<<dim3(DMODEL / 128, PPAD / 256), 512, 73728, stream>>>(hb, w3t, out, tok, wg, offp);
}

// Round 7
// 820.280 us; speedup vs baseline: 1.0518x; 1.0518x over previous
//
#include <hip/hip_runtime.h>
#include <hip/hip_bf16.h>

typedef __attribute__((ext_vector_type(8))) short short8;
typedef __attribute__((ext_vector_type(4))) float f32x4;
typedef unsigned short u16;
typedef unsigned int u32;

#define NTOK   8192
#define DMODEL 1024
#define DFF    4096
#define NEXP   8
#define NPAIR  (NTOK * 2)
#define PADM   256            // per-expert padding
#define MT1    72             // ceil((16384 + 8*255)/256)
#define PPAD   (MT1 * PADM)   // 18432

// ---- workspace layout (bytes) ----
#define OFF_XB   0ull
#define OFF_W1T  (OFF_XB  + (size_t)NTOK * DMODEL * 2)
#define OFF_W2T  (OFF_W1T + (size_t)NEXP * DFF * DMODEL * 2)
#define OFF_W3T  (OFF_W2T + (size_t)NEXP * DFF * DMODEL * 2)
#define OFF_H    (OFF_W3T + (size_t)NEXP * DMODEL * DFF * 2)
#define OFF_TOK  (OFF_H   + (size_t)PPAD * DFF * 2)
#define OFF_WGT  (OFF_TOK + (size_t)PPAD * 4)
#define OFF_CNT  (OFF_WGT + (size_t)PPAD * 4)
#define OFF_CUR  (OFF_CNT + 64)
#define OFF_OFFP (OFF_CUR + 64)
#define WS_END   (OFF_OFFP + 64)

#define GLOAD16(gp, lp)                                                        \
  __builtin_amdgcn_global_load_lds(                                            \
      (const __attribute__((address_space(1))) u32*)(gp),                      \
      (__attribute__((address_space(3))) u32*)(lp), 16, 0, 0)

__device__ __forceinline__ u16 f2bu(float f) {
  __hip_bfloat16 b = __float2bfloat16(f);
  return __builtin_bit_cast(u16, b);
}

// ---------------- conversion kernels ----------------

__global__ __launch_bounds__(256) void cvt_x_k(const float* __restrict__ x,
                                               u16* __restrict__ xb) {
  int i = blockIdx.x * 256 + threadIdx.x;
  float4 v = ((const float4*)x)[i];
  unsigned long long pk = (unsigned long long)f2bu(v.x) |
                          ((unsigned long long)f2bu(v.y) << 16) |
                          ((unsigned long long)f2bu(v.z) << 32) |
                          ((unsigned long long)f2bu(v.w) << 48);
  ((unsigned long long*)xb)[i] = pk;
}

// transpose [R][C] fp32 -> [C][R] bf16, batched over blockIdx.z
__global__ __launch_bounds__(256) void tr_cvt_k(const float* __restrict__ src,
                                                u16* __restrict__ dst, int R, int C) {
  src += (size_t)blockIdx.z * R * C;
  dst += (size_t)blockIdx.z * R * C;
  int c0 = blockIdx.x * 64, r0 = blockIdx.y * 64;
  __shared__ float tile[64][65];
  int tid = threadIdx.x;
  int f4 = tid & 15, rr = tid >> 4;
#pragma unroll
  for (int p = 0; p < 4; ++p) {
    int r = rr + p * 16;
    float4 v = *(const float4*)(src + (size_t)(r0 + r) * C + c0 + f4 * 4);
    tile[r][f4 * 4 + 0] = v.x; tile[r][f4 * 4 + 1] = v.y;
    tile[r][f4 * 4 + 2] = v.z; tile[r][f4 * 4 + 3] = v.w;
  }
  __syncthreads();
  int ch = tid & 7, cc = tid >> 3;
#pragma unroll
  for (int p = 0; p < 2; ++p) {
    int c = cc + p * 32;
    short8 s;
#pragma unroll
    for (int j = 0; j < 8; ++j) s[j] = (short)f2bu(tile[ch * 8 + j][c]);
    *(short8*)(dst + (size_t)(c0 + c) * R + r0 + ch * 8) = s;
  }
}

// ---------------- routing kernels ----------------

__global__ __launch_bounds__(256) void count_k(const int* __restrict__ ei,
                                               int* __restrict__ cnt) {
  int i = blockIdx.x * 256 + threadIdx.x;
  atomicAdd(&cnt[ei[i]], 1);
}

__global__ void scan_k(const int* __restrict__ cnt, int* __restrict__ offp) {
  if (threadIdx.x == 0) {
    int a = 0;
#pragma unroll
    for (int e = 0; e < NEXP; ++e) { offp[e] = a; a += (cnt[e] + PADM - 1) & ~(PADM - 1); }
    offp[NEXP] = a;
  }
}

__global__ __launch_bounds__(256) void scatter_k(const int* __restrict__ ei,
                                                 const float* __restrict__ ew,
                                                 const int* __restrict__ offp,
                                                 int* __restrict__ cur,
                                                 int* __restrict__ tok,
                                                 float* __restrict__ wg) {
  int i = blockIdx.x * 256 + threadIdx.x;
  int e = ei[i];
  int p = offp[e] + atomicAdd(&cur[e], 1);
  tok[p] = i >> 1;
  wg[p] = ew[i];
}

// ---------------- stage 1: h = silu(x@W1) * (x@W2), grouped ----------------
// r5 kernel verbatim (best measured: 321 us, MfmaUtil 40.5%, 0 conflicts).
// 3-buffer, BK=32, counted vmcnt(4), 1 barrier/step, MFMA 16x16x32.

#define S1_BUF 16384   // u16 per buffer: A 8192 | B1 4096 | B2 4096
#define S1_NK  32      // 1024 / 32

__global__ __launch_bounds__(512, 2) void stage1_k(const u16* __restrict__ xb,
                                                   const u16* __restrict__ w1t,
                                                   const u16* __restrict__ w2t,
                                                   u16* __restrict__ h,
                                                   const int* __restrict__ tok,
                                                   const int* __restrict__ offp) {
  extern __shared__ __align__(16) u16 lds[];   // 3 * 32 KB = 98304 B
  const int r0 = blockIdx.y * PADM;
  if (r0 >= offp[NEXP]) return;
  int e = 0;
#pragma unroll
  for (int q = 0; q < 7; ++q) e += (offp[e + 1] <= r0) ? 1 : 0;
  const int n0 = blockIdx.x * 128;
  const int tid = threadIdx.x;
  const int lane = tid & 63, w = tid >> 6;
  const int wm = w >> 2, wn = w & 3;

  const int sl = lane & 3, rl = lane >> 2;
  const u16* aga[2];
  int adb[2];
#pragma unroll
  for (int j = 0; j < 2; ++j) {
    int row = w * 32 + j * 16 + rl;
    int t = tok[r0 + row];
    aga[j] = xb + (size_t)t * DMODEL + ((sl ^ ((row >> 1) & 3)) << 3);
    adb[j] = (w * 32 + j * 16) * 32;
  }
  const u16* w1e = w1t + (size_t)e * DFF * DMODEL;
  const u16* w2e = w2t + (size_t)e * DFF * DMODEL;
  const u16* bg1; const u16* bg2;
  int bdb;
  {
    int row = w * 16 + rl;
    size_t ro = (size_t)(n0 + row) * DMODEL + ((sl ^ ((row >> 1) & 3)) << 3);
    bg1 = w1e + ro; bg2 = w2e + ro;
    bdb = (w * 16) * 32;
  }

  int aoff[8], boff[2];
  {
    int ks = lane >> 4;
#pragma unroll
    for (int mi = 0; mi < 8; ++mi) {
      int row = wm * 128 + mi * 16 + (lane & 15);
      aoff[mi] = row * 32 + ((ks ^ ((row >> 1) & 3)) << 3);
    }
#pragma unroll
    for (int ni = 0; ni < 2; ++ni) {
      int col = wn * 32 + ni * 16 + (lane & 15);
      boff[ni] = col * 32 + ((ks ^ ((col >> 1) & 3)) << 3);
    }
  }

  f32x4 accg[8][2], accv[8][2];
  const f32x4 zero = {0.f, 0.f, 0.f, 0.f};
#pragma unroll
  for (int mi = 0; mi < 8; ++mi)
#pragma unroll
    for (int ni = 0; ni < 2; ++ni) { accg[mi][ni] = zero; accv[mi][ni] = zero; }

#define S1_ISSUE(Q, KO)                                                        \
  do {                                                                         \
    GLOAD16(aga[0] + (KO), (Q) + adb[0]);                                      \
    GLOAD16(aga[1] + (KO), (Q) + adb[1]);                                      \
    GLOAD16(bg1 + (KO), (Q) + 8192 + bdb);                                     \
    GLOAD16(bg2 + (KO), (Q) + 12288 + bdb);                                    \
  } while (0)

  S1_ISSUE(lds, 0);
  S1_ISSUE(lds + S1_BUF, 32);
  asm volatile("s_waitcnt vmcnt(4)" ::: "memory");
  __builtin_amdgcn_s_barrier();
  __builtin_amdgcn_sched_barrier(0);

#define S1_STEP(P, KC, ISSUE)                                                  \
  {                                                                            \
    const u16* Ab  = lds + (P) * S1_BUF;                                       \
    const u16* B1b = Ab + 8192;                                                \
    const u16* B2b = Ab + 12288;                                               \
    short8 af[8], b1f[2], b2f[2];                                              \
    _Pragma("unroll") for (int mi = 0; mi < 8; ++mi)                           \
      af[mi] = *(const short8*)(Ab + aoff[mi]);                                \
    _Pragma("unroll") for (int ni = 0; ni < 2; ++ni) {                         \
      b1f[ni] = *(const short8*)(B1b + boff[ni]);                              \
      b2f[ni] = *(const short8*)(B2b + boff[ni]);                              \
    }                                                                          \
    if (ISSUE) S1_ISSUE(lds + (((P) + 2) % 3) * S1_BUF, ((KC) + 2) * 32);      \
    __builtin_amdgcn_s_setprio(1);                                             \
    _Pragma("unroll") for (int mi = 0; mi < 8; ++mi)                           \
      _Pragma("unroll") for (int ni = 0; ni < 2; ++ni) {                       \
        accg[mi][ni] = __builtin_amdgcn_mfma_f32_16x16x32_bf16(                \
            af[mi], b1f[ni], accg[mi][ni], 0, 0, 0);                           \
        accv[mi][ni] = __builtin_amdgcn_mfma_f32_16x16x32_bf16(                \
            af[mi], b2f[ni], accv[mi][ni], 0, 0, 0);                           \
      }                                                                        \
    __builtin_amdgcn_s_setprio(0);                                             \
    if (ISSUE) asm volatile("s_waitcnt vmcnt(4)" ::: "memory");                \
    else       asm volatile("s_waitcnt vmcnt(0)" ::: "memory");                \
    __builtin_amdgcn_s_barrier();                                              \
    __builtin_amdgcn_sched_barrier(0);                                         \
  }

  for (int kc = 0; kc < S1_NK - 2; kc += 3) {
    S1_STEP(0, kc, 1)
    S1_STEP(1, kc + 1, 1)
    S1_STEP(2, kc + 2, 1)
  }
  S1_STEP(0, S1_NK - 2, 0)
  S1_STEP(1, S1_NK - 1, 0)
#undef S1_STEP
#undef S1_ISSUE

  const int prow = r0 + wm * 128 + ((lane >> 4) << 2);
  const int pcol = n0 + wn * 32 + (lane & 15);
#pragma unroll
  for (int mi = 0; mi < 8; ++mi)
#pragma unroll
    for (int ni = 0; ni < 2; ++ni)
#pragma unroll
      for (int j = 0; j < 4; ++j) {
        float g = accg[mi][ni][j];
        float v = accv[mi][ni][j];
        float s = g / (1.f + __expf(-g));
        h[(size_t)(prow + mi * 16 + j) * DFF + (pcol + ni * 16)] = f2bu(s * v);
      }
}

// ---------------- stage 2: out += p * (h @ W3), grouped ----------------
// 3-buffer counted-vmcnt pipeline, BK=64 (64 steps -> same FLOP/step as
// stage1), tile 256x128, 512 thr (8 waves = 4M x 2N, wave tile 64x64).
// LDS 3 x 48 KB = 144 KB, 1 block/CU. 8-slot seg^(row&7) swizzle (r1-proven,
// 0 conflicts). Per step: 16 ds_read_b128 + 6 global_load_lds (buf s+2)
// + 32 MFMA + vmcnt(6) + 1 barrier.

#define S2_BUF 24576   // u16 per buffer: A 16384 (256x64) | B 8192 (128x64)
#define S2_NK  64      // 4096 / 64

__global__ __launch_bounds__(512, 2) void stage2_k(const u16* __restrict__ h,
                                                   const u16* __restrict__ w3t,
                                                   float* __restrict__ out,
                                                   const int* __restrict__ tok,
                                                   const float* __restrict__ wg,
                                                   const int* __restrict__ offp) {
  extern __shared__ __align__(16) u16 lds[];   // 3 * 49152 B = 147456 B
  const int r0 = blockIdx.y * 256;
  if (r0 >= offp[NEXP]) return;
  int e = 0;
#pragma unroll
  for (int q = 0; q < 7; ++q) e += (offp[e + 1] <= r0) ? 1 : 0;
  const int n0 = blockIdx.x * 128;
  const int tid = threadIdx.x;
  const int lane = tid & 63, w = tid >> 6;
  const int wm = w >> 1, wn = w & 1;
  const int lr = lane >> 3, seg = lane & 7;

  // staging: A 4 issues (32 KB), B 2 issues (16 KB); source-side swizzle
  const u16* aga[4];
  int adb[4];
#pragma unroll
  for (int j = 0; j < 4; ++j) {
    int row = w * 32 + j * 8 + lr;
    aga[j] = h + (size_t)(r0 + row) * DFF + ((seg ^ (row & 7)) << 3);
    adb[j] = (w * 32 + j * 8) * 64;
  }
  const u16* w3e = w3t + (size_t)e * DMODEL * DFF;
  const u16* bga[2];
  int bdb[2];
#pragma unroll
  for (int j = 0; j < 2; ++j) {
    int row = w * 16 + j * 8 + lr;
    bga[j] = w3e + (size_t)(n0 + row) * DFF + ((seg ^ (row & 7)) << 3);
    bdb[j] = (w * 16 + j * 8) * 64;
  }

  int aoff[4][2], boff[4][2];
  {
    int ks = lane >> 4;
#pragma unroll
    for (int mi = 0; mi < 4; ++mi)
#pragma unroll
      for (int kk = 0; kk < 2; ++kk) {
        int row = wm * 64 + mi * 16 + (lane & 15);
        aoff[mi][kk] = row * 64 + (((kk * 4 + ks) ^ (row & 7)) << 3);
      }
#pragma unroll
    for (int ni = 0; ni < 4; ++ni)
#pragma unroll
      for (int kk = 0; kk < 2; ++kk) {
        int col = wn * 64 + ni * 16 + (lane & 15);
        boff[ni][kk] = col * 64 + (((kk * 4 + ks) ^ (col & 7)) << 3);
      }
  }

  f32x4 acc[4][4];
  const f32x4 zero = {0.f, 0.f, 0.f, 0.f};
#pragma unroll
  for (int mi = 0; mi < 4; ++mi)
#pragma unroll
    for (int ni = 0; ni < 4; ++ni) acc[mi][ni] = zero;

#define S2_ISSUE(Q, KO)                                                        \
  do {                                                                         \
    GLOAD16(aga[0] + (KO), (Q) + adb[0]);                                      \
    GLOAD16(aga[1] + (KO), (Q) + adb[1]);                                      \
    GLOAD16(aga[2] + (KO), (Q) + adb[2]);                                      \
    GLOAD16(aga[3] + (KO), (Q) + adb[3]);                                      \
    GLOAD16(bga[0] + (KO), (Q) + 16384 + bdb[0]);                              \
    GLOAD16(bga[1] + (KO), (Q) + 16384 + bdb[1]);                              \
  } while (0)

  S2_ISSUE(lds, 0);
  S2_ISSUE(lds + S2_BUF, 64);
  asm volatile("s_waitcnt vmcnt(6)" ::: "memory");
  __builtin_amdgcn_s_barrier();
  __builtin_amdgcn_sched_barrier(0);

#define S2_STEP(P, KC, ISSUE)                                                  \
  {                                                                            \
    const u16* Ab = lds + (P) * S2_BUF;                                        \
    const u16* Bb = Ab + 16384;                                                \
    short8 af[4][2], bf[4][2];                                                 \
    _Pragma("unroll") for (int mi = 0; mi < 4; ++mi)                           \
      _Pragma("unroll") for (int kk = 0; kk < 2; ++kk)                         \
        af[mi][kk] = *(const short8*)(Ab + aoff[mi][kk]);                      \
    _Pragma("unroll") for (int ni = 0; ni < 4; ++ni)                           \
      _Pragma("unroll") for (int kk = 0; kk < 2; ++kk)                         \
        bf[ni][kk] = *(const short8*)(Bb + boff[ni][kk]);                      \
    if (ISSUE) S2_ISSUE(lds + (((P) + 2) % 3) * S2_BUF, ((KC) + 2) * 64);      \
    __builtin_amdgcn_s_setprio(1);                                             \
    _Pragma("unroll") for (int kk = 0; kk < 2; ++kk)                           \
      _Pragma("unroll") for (int mi = 0; mi < 4; ++mi)                         \
        _Pragma("unroll") for (int ni = 0; ni < 4; ++ni)                       \
          acc[mi][ni] = __builtin_amdgcn_mfma_f32_16x16x32_bf16(               \
              af[mi][kk], bf[ni][kk], acc[mi][ni], 0, 0, 0);                   \
    __builtin_amdgcn_s_setprio(0);                                             \
    if (ISSUE) asm volatile("s_waitcnt vmcnt(6)" ::: "memory");                \
    else       asm volatile("s_waitcnt vmcnt(0)" ::: "memory");                \
    __builtin_amdgcn_s_barrier();                                              \
    __builtin_amdgcn_sched_barrier(0);                                         \
  }

  for (int kc = 0; kc < S2_NK - 4; kc += 3) {
    S2_STEP(0, kc, 1)
    S2_STEP(1, kc + 1, 1)
    S2_STEP(2, kc + 2, 1)
  }
  S2_STEP(0, S2_NK - 4, 1)
  S2_STEP(1, S2_NK - 3, 1)
  S2_STEP(2, S2_NK - 2, 0)
  S2_STEP(0, S2_NK - 1, 0)
#undef S2_STEP
#undef S2_ISSUE

  const int prow = r0 + wm * 64 + ((lane >> 4) << 2);
  const int pcolb = n0 + wn * 64 + (lane & 15);
#pragma unroll
  for (int mi = 0; mi < 4; ++mi)
#pragma unroll
    for (int j = 0; j < 4; ++j) {
      int pos = prow + mi * 16 + j;
      float p = wg[pos];
      if (p != 0.f) {
        int t = tok[pos];
#pragma unroll
        for (int ni = 0; ni < 4; ++ni)
          atomicAdd(&out[(size_t)t * DMODEL + pcolb + ni * 16], p * acc[mi][ni][j]);
      }
    }
}

// ---------------- launch ----------------

extern "C" void kernel_launch(void* const* d_in, const int* in_sizes, int n_in,
                              void* d_out, int out_size, void* d_ws, size_t ws_size,
                              hipStream_t stream) {
  (void)in_sizes; (void)n_in;
  const float* x  = (const float*)d_in[0];
  const int*   ei = (const int*)d_in[1];
  const float* ew = (const float*)d_in[2];
  const float* w1 = (const float*)d_in[3];
  const float* w2 = (const float*)d_in[4];
  const float* w3 = (const float*)d_in[5];
  float* out = (float*)d_out;
  char* ws = (char*)d_ws;

  hipMemsetAsync(out, 0, (size_t)out_size * sizeof(float), stream);
  if (ws_size < WS_END) return;   // ws too small: leave zeros (diagnosable absmax)

  u16* xb   = (u16*)(ws + OFF_XB);
  u16* w1t  = (u16*)(ws + OFF_W1T);
  u16* w2t  = (u16*)(ws + OFF_W2T);
  u16* w3t  = (u16*)(ws + OFF_W3T);
  u16* hb   = (u16*)(ws + OFF_H);
  int* tok  = (int*)(ws + OFF_TOK);
  float* wg = (float*)(ws + OFF_WGT);
  int* cnt  = (int*)(ws + OFF_CNT);
  int* cur  = (int*)(ws + OFF_CUR);
  int* offp = (int*)(ws + OFF_OFFP);

  hipMemsetAsync(ws + OFF_TOK, 0, (size_t)(WS_END - OFF_TOK), stream);

  hipFuncSetAttribute(reinterpret_cast<const void*>(stage1_k),
                      hipFuncAttributeMaxDynamicSharedMemorySize, 98304);
  hipFuncSetAttribute(reinterpret_cast<const void*>(stage2_k),
                      hipFuncAttributeMaxDynamicSharedMemorySize, 147456);

  cvt_x_k<<<dim3(NTOK * DMODEL / 4 / 256), 256, 0, stream>>>(x, xb);
  tr_cvt_k<<<dim3(DFF / 64, DMODEL / 64, NEXP), 256, 0, stream>>>(w1, w1t, DMODEL, DFF);
  tr_cvt_k<<<dim3(DFF / 64, DMODEL / 64, NEXP), 256, 0, stream>>>(w2, w2t, DMODEL, DFF);
  tr_cvt_k<<<dim3(DMODEL / 64, DFF / 64, NEXP), 256, 0, stream>>>(w3, w3t, DFF, DMODEL);
  count_k<<<dim3(NPAIR / 256), 256, 0, stream>>>(ei, cnt);
  scan_k<<<1, 64, 0, stream>>>(cnt, offp);
  scatter_k<<<dim3(NPAIR / 256), 256, 0, stream>>>(ei, ew, offp, cur, tok, wg);
  stage1_k<<<dim3(DFF / 128, MT1), 512, 98304, stream>>>(xb, w1t, w2t, hb, tok, offp);
  stage2_k<<<dim3(DMODEL / 128, PPAD / 256), 512, 147456, stream>>>(hb, w3t, out, tok, wg, offp);
}